// Round 5
// baseline (996.474 us; speedup 1.0000x reference)
//
#include <hip/hip_runtime.h>
#include <cstddef>

#define T_STEPS  512
#define D_IN     5
#define NB       16      // batch elements per block
#define NTHREADS 512     // 8 waves; each wave owns 2 L0 M-tiles + 2 L1 M-tiles

typedef __attribute__((ext_vector_type(8))) short bf16x8;   // 8 bf16 (4 VGPRs/AGPRs)
typedef __attribute__((ext_vector_type(4))) float f32x4;    // MFMA C/D

// Inline-asm MFMA: A pinned in AGPRs ("a"), B/C/D in VGPRs. INIT form folds the
// bias in as srcC (D != C legal), ACC form chains D==C (HW-supported, no nops).
#define MFMA_INIT(D, A, B, C) \
    asm("v_mfma_f32_16x16x32_bf16 %0, %1, %2, %3" : "=&v"(D) : "a"(A), "v"(B), "v"(C))
#define MFMA_ACC(D, A, B) \
    asm("v_mfma_f32_16x16x32_bf16 %0, %1, %2, %0" : "+v"(D) : "a"(A), "v"(B))

__device__ __forceinline__ float fast_sigmoid(float x) {
    return __fdividef(1.0f, 1.0f + __expf(-x));
}
__device__ __forceinline__ float fast_tanh(float x) {
    return 1.0f - __fdividef(2.0f, 1.0f + __expf(2.0f * x));
}

__device__ __forceinline__ unsigned short f2bf(float f) {   // RTNE fp32->bf16 bits
    unsigned int u = __float_as_uint(f);
    u += 0x7FFFu + ((u >> 16) & 1u);
    return (unsigned short)(u >> 16);
}
__device__ __forceinline__ float bf2f(unsigned short h) {
    return __uint_as_float(((unsigned int)h) << 16);
}
__device__ __forceinline__ void split8(const float* wv, bf16x8& hi, bf16x8& lo) {
    #pragma unroll
    for (int j = 0; j < 8; ++j) {
        unsigned short h = f2bf(wv[j]);
        unsigned short l = f2bf(wv[j] - bf2f(h));
        hi[j] = (short)h;
        lo[j] = (short)l;
    }
}

// h-plane swizzle: row = 128 u16 = 16 x 16B blocks; block j of row n lives at
// j ^ (n & 7). Reads hit the b128 floor; b32 packed writes spread over all 32
// banks 2-way (free).

// Row permutation: MFMA row m of tile Mt=(w*2+t) maps to unit u = w*8 +
// (m>>2)*2 + t, gate = m&3 (orig weight row gate*64+u). C/D layout
// (col=lane&15, row=quad*4+r) then gives each lane acc = (i,f,g,o) of ONE
// (u = w*8+quad*2+t, b = lane&15): register-local cell update, and the two
// t-values of a lane are ADJACENT u -> one packed b32 h-write.

__global__ __launch_bounds__(NTHREADS, 2)
void lstm_stack_mfma4(const float* __restrict__ x,
                      const float* __restrict__ W_ih0,
                      const float* __restrict__ W_hh0,
                      const float* __restrict__ b_ih0,
                      const float* __restrict__ b_hh0,
                      const float* __restrict__ W_ih1,
                      const float* __restrict__ W_hh1,
                      const float* __restrict__ b_ih1,
                      const float* __restrict__ b_hh1,
                      const float* __restrict__ W1,
                      const float* __restrict__ b1,
                      const float* __restrict__ W2,
                      const float* __restrict__ b2,
                      float* __restrict__ out)
{
    __shared__ alignas(16) unsigned short h_hi[2][NB][128];  // k 0..63=h1, 64..127=h2 (swizzled)
    __shared__ alignas(16) unsigned short x_pack[2][NB][32]; // [x_hi(5)|x_lo(5)|x_hi(5)|0..]
    __shared__ alignas(16) float h2f[NB][68];   // exact fp32 h2(T-1) for FC head
    __shared__ alignas(16) float zb[NB][36];    // FC-head z buffer

    const int tid  = threadIdx.x;
    const int b0   = blockIdx.x * NB;
    const int w    = tid >> 6;        // wave 0..7
    const int lane = tid & 63;
    const int n16  = lane & 15;       // A row (within tile) / B col / C col
    const int quad = lane >> 4;       // A k-group / C row-group

    // ---------------- persistent register state ----------------
    bf16x8 aXp[2];                    // L0 packed x-weights [Wx_hi|Wx_hi|Wx_lo]
    bf16x8 a0[2][4];                  // L0 h1: [Whi k0, Whi k1, Wlo k0, Wlo k1]
    bf16x8 a1[2][8];                  // L1 [h1;h2]: [Whi k0..3, Wlo k0..3]
    f32x4  bc0[2], bc1[2];            // bias C-operands
    float  c0[2] = {0.f, 0.f};        // L0 cell state (u = w*8+quad*2+t, b = n16)
    float  c1[2] = {0.f, 0.f};        // L1 cell state

    #pragma unroll
    for (int t = 0; t < 2; ++t) {
        const int u_a = w * 8 + (n16 >> 2) * 2 + t;   // permuted u of this A row
        const int g_a = n16 & 3;                      // gate of this A row
        const int r0  = g_a * 64 + u_a;               // original weight row
        float wv[8];
        // packed x K-tile: slots 0-4 Wx_hi, 5-9 Wx_hi, 10-14 Wx_lo, 15.. 0
        #pragma unroll
        for (int j = 0; j < 8; ++j) {
            const int k = quad * 8 + j;
            float v = 0.f;
            if (k < 2 * D_IN) {                       // hi copy
                const float wf = W_ih0[r0 * D_IN + (k < D_IN ? k : k - D_IN)];
                v = bf2f(f2bf(wf));
            } else if (k < 3 * D_IN) {                // lo copy
                const float wf = W_ih0[r0 * D_IN + (k - 2 * D_IN)];
                v = wf - bf2f(f2bf(wf));
            }
            wv[j] = v;
        }
        bf16x8 dum;
        split8(wv, aXp[t], dum);      // values already bf16-exact; hi == value
        #pragma unroll
        for (int kt = 0; kt < 2; ++kt) {
            #pragma unroll
            for (int j = 0; j < 8; ++j) wv[j] = W_hh0[r0 * 64 + kt * 32 + quad * 8 + j];
            split8(wv, a0[t][kt], a0[t][2 + kt]);
        }
        #pragma unroll
        for (int kt = 0; kt < 4; ++kt) {
            const int kg = kt * 32 + quad * 8;
            #pragma unroll
            for (int j = 0; j < 8; ++j)
                wv[j] = (kg < 64) ? W_ih1[r0 * 64 + kg + j] : W_hh1[r0 * 64 + (kg - 64) + j];
            split8(wv, a1[t][kt], a1[t][4 + kt]);
        }
        const int u_c = w * 8 + quad * 2 + t;
        #pragma unroll
        for (int r = 0; r < 4; ++r) {
            bc0[t][r] = b_ih0[r * 64 + u_c] + b_hh0[r * 64 + u_c];
            bc1[t][r] = b_ih1[r * 64 + u_c] + b_hh1[r * 64 + u_c];
        }
    }

    // ---------------- LDS init ----------------
    for (int i = tid; i < 2 * NB * 128; i += NTHREADS) (&h_hi[0][0][0])[i] = 0;
    for (int i = tid; i < 2 * NB * 32; i += NTHREADS) (&x_pack[0][0][0])[i] = 0;
    __syncthreads();
    const int xb = tid / D_IN, xd = tid % D_IN;   // x-staging role (tid < 80)
    const bool xrole = (tid < NB * D_IN);
    if (xrole) {   // x(t=0) into buffer 0
        const float xv = x[((size_t)(b0 + xb) * T_STEPS) * D_IN + xd];
        const unsigned short xh = f2bf(xv);
        const unsigned short xl = f2bf(xv - bf2f(xh));
        x_pack[0][xb][xd]             = xh;
        x_pack[0][xb][D_IN + xd]      = xl;
        x_pack[0][xb][2 * D_IN + xd]  = xh;
    }
    __syncthreads();

    const int swz8 = (w ^ (n16 & 7)) << 3;   // swizzled base of this lane's write block

    // step s: reads buf[s&1] = {h1(s-1), h2(s-2), x(s)}; computes gates0(s),
    // gates1(s-1); register-local epilogue; writes h1(s), h2(s-1), x(s+1)
    #pragma unroll 1
    for (int s = 0; s <= T_STEPS; ++s) {
        const int rb = s & 1, wbuf = rb ^ 1;

        float xv = 0.f;   // prefetch x(s+1)
        if (xrole && (s + 1) < T_STEPS)
            xv = x[((size_t)(b0 + xb) * T_STEPS + (s + 1)) * D_IN + xd];

        const bf16x8 bxp = *reinterpret_cast<const bf16x8*>(&x_pack[rb][n16][quad * 8]);
        bf16x8 bhh[4];
        #pragma unroll
        for (int kt = 0; kt < 4; ++kt)
            bhh[kt] = *reinterpret_cast<const bf16x8*>(
                &h_hi[rb][n16][((kt * 4 + quad) ^ (n16 & 7)) * 8]);

        f32x4 acc0[2], acc1[2];
        #pragma unroll
        for (int t = 0; t < 2; ++t) {
            MFMA_INIT(acc0[t], aXp[t], bxp, bc0[t]);       // bias + all 3 x split terms
            MFMA_ACC(acc0[t], a0[t][0], bhh[0]);           // Whi . h1
            MFMA_ACC(acc0[t], a0[t][1], bhh[1]);
            MFMA_ACC(acc0[t], a0[t][2], bhh[0]);           // Wlo . h1
            MFMA_ACC(acc0[t], a0[t][3], bhh[1]);

            MFMA_INIT(acc1[t], a1[t][0], bhh[0], bc1[t]);  // Whi . [h1;h2]
            MFMA_ACC(acc1[t], a1[t][1], bhh[1]);
            MFMA_ACC(acc1[t], a1[t][2], bhh[2]);
            MFMA_ACC(acc1[t], a1[t][3], bhh[3]);
            MFMA_ACC(acc1[t], a1[t][4], bhh[0]);           // Wlo . [h1;h2]
            MFMA_ACC(acc1[t], a1[t][5], bhh[1]);
            MFMA_ACC(acc1[t], a1[t][6], bhh[2]);
            MFMA_ACC(acc1[t], a1[t][7], bhh[3]);
        }
        // hazard spacing: MFMA D-write -> VALU read needs ~16 cyc
        asm("s_nop 7\n\ts_nop 7"
            : "+v"(acc0[0]), "+v"(acc0[1]), "+v"(acc1[0]), "+v"(acc1[1]));

        if (s < T_STEPS) {          // L0 epilogue: h1(s), c1 -- one packed b32 write
            unsigned int pk = 0;
            #pragma unroll
            for (int t = 0; t < 2; ++t) {
                const float i_ = fast_sigmoid(acc0[t][0]);
                const float f_ = fast_sigmoid(acc0[t][1]);
                const float g_ = fast_tanh(acc0[t][2]);
                const float o_ = fast_sigmoid(acc0[t][3]);
                const float c  = f_ * c0[t] + i_ * g_;
                c0[t] = c;
                const float h  = o_ * fast_tanh(c);
                pk |= ((unsigned int)f2bf(h)) << (16 * t);
            }
            *reinterpret_cast<unsigned int*>(&h_hi[wbuf][n16][swz8 + quad * 2]) = pk;
        }
        if (s > 0) {                // L1 epilogue: h2(s-1), c2
            unsigned int pk = 0;
            #pragma unroll
            for (int t = 0; t < 2; ++t) {
                const float i_ = fast_sigmoid(acc1[t][0]);
                const float f_ = fast_sigmoid(acc1[t][1]);
                const float g_ = fast_tanh(acc1[t][2]);
                const float o_ = fast_sigmoid(acc1[t][3]);
                const float c  = f_ * c1[t] + i_ * g_;
                c1[t] = c;
                const float h  = o_ * fast_tanh(c);
                pk |= ((unsigned int)f2bf(h)) << (16 * t);
                if (s == T_STEPS) h2f[n16][w * 8 + quad * 2 + t] = h;
            }
            *reinterpret_cast<unsigned int*>(&h_hi[wbuf][n16][64 + swz8 + quad * 2]) = pk;
        }
        if (xrole && (s + 1) < T_STEPS) {   // stage x(s+1) packed
            const unsigned short xh = f2bf(xv);
            const unsigned short xl = f2bf(xv - bf2f(xh));
            x_pack[wbuf][xb][xd]            = xh;
            x_pack[wbuf][xb][D_IN + xd]     = xl;
            x_pack[wbuf][xb][2 * D_IN + xd] = xh;
        }
        __syncthreads();
    }

    // ---------------- FC head: relu(h2_T @ W1^T + b1) @ W2^T + b2 ----------------
    {
        const int bb = tid >> 5;            // 0..15
        const int k  = tid & 31;            // 0..31
        float a = b1[k];
        #pragma unroll 16
        for (int j = 0; j < 64; ++j)
            a = fmaf(W1[k * 64 + j], h2f[bb][j], a);
        zb[bb][k] = fmaxf(a, 0.0f);
    }
    __syncthreads();
    if (tid < NB) {
        float a = b2[0];
        #pragma unroll
        for (int k = 0; k < 32; ++k) a = fmaf(W2[k], zb[tid][k], a);
        out[b0 + tid] = a;
    }
}

extern "C" void kernel_launch(void* const* d_in, const int* in_sizes, int n_in,
                              void* d_out, int out_size, void* d_ws, size_t ws_size,
                              hipStream_t stream) {
    (void)in_sizes; (void)n_in; (void)d_ws; (void)ws_size;
    const float* xp     = (const float*)d_in[0];
    const float* W_ih0  = (const float*)d_in[1];
    const float* W_hh0  = (const float*)d_in[2];
    const float* b_ih0  = (const float*)d_in[3];
    const float* b_hh0  = (const float*)d_in[4];
    const float* W_ih1  = (const float*)d_in[5];
    const float* W_hh1  = (const float*)d_in[6];
    const float* b_ih1  = (const float*)d_in[7];
    const float* b_hh1  = (const float*)d_in[8];
    const float* W1     = (const float*)d_in[9];
    const float* b1     = (const float*)d_in[10];
    const float* W2     = (const float*)d_in[11];
    const float* b2     = (const float*)d_in[12];
    float* outp = (float*)d_out;

    const int nblocks = out_size / NB;   // 4096/16 = 256, one block per CU
    hipLaunchKernelGGL(lstm_stack_mfma4, dim3(nblocks), dim3(NTHREADS), 0, stream,
                       xp, W_ih0, W_hh0, b_ih0, b_hh0,
                       W_ih1, W_hh1, b_ih1, b_hh1,
                       W1, b1, W2, b2, outp);
}

// Round 7
// 943.760 us; speedup vs baseline: 1.0559x; 1.0559x over previous
//
#include <hip/hip_runtime.h>
#include <cstddef>

#define T_STEPS  512
#define D_IN     5
#define NB       16      // batch elements per block
#define NTHREADS 1024    // 16 waves; each wave owns 1 L0 M-tile + 1 L1 M-tile

typedef __attribute__((ext_vector_type(8))) short bf16x8;   // 8 bf16 (4 regs)
typedef __attribute__((ext_vector_type(4))) float f32x4;    // MFMA C/D

// A pinned in AGPRs ("a"); B, C, D in VGPRs (srcC and vDst must be the same
// register file -- AGPR srcC with VGPR dst does not encode).
#define MFMA_INIT(D, A, B, C) \
    asm("v_mfma_f32_16x16x32_bf16 %0, %1, %2, %3" : "=&v"(D) : "a"(A), "v"(B), "v"(C))
#define MFMA_ACC(D, A, B) \
    asm("v_mfma_f32_16x16x32_bf16 %0, %1, %2, %0" : "+v"(D) : "a"(A), "v"(B))

__device__ __forceinline__ float fast_sigmoid(float x) {
    return __fdividef(1.0f, 1.0f + __expf(-x));
}
__device__ __forceinline__ float fast_tanh(float x) {
    return 1.0f - __fdividef(2.0f, 1.0f + __expf(2.0f * x));
}

__device__ __forceinline__ unsigned short f2bf(float f) {   // RTNE fp32->bf16 bits
    unsigned int u = __float_as_uint(f);
    u += 0x7FFFu + ((u >> 16) & 1u);
    return (unsigned short)(u >> 16);
}
__device__ __forceinline__ float bf2f(unsigned short h) {
    return __uint_as_float(((unsigned int)h) << 16);
}
__device__ __forceinline__ void split8(const float* wv, bf16x8& hi, bf16x8& lo) {
    #pragma unroll
    for (int j = 0; j < 8; ++j) {
        unsigned short h = f2bf(wv[j]);
        unsigned short l = f2bf(wv[j] - bf2f(h));
        hi[j] = (short)h;
        lo[j] = (short)l;
    }
}

// h-plane swizzle: row = 128 u16 = 16 x 16B blocks; block j of row n lives at
// j ^ (n & 7). b128 reads conflict-free; scalar b16 writes spread across all
// bank-quads 2-way (free).
__device__ __forceinline__ int hswz(int n, int col) {
    return (((col >> 3) ^ (n & 7)) << 3) | (col & 7);
}

// Row permutation: wave w owns M-tile w of both layers; A-row m -> unit
// u = w*4 + (m>>2), gate = m&3 (orig weight row gate*64+u). C/D layout
// (col=lane&15, row=quad*4+r) gives each lane acc = (i,f,g,o) of ONE
// (u = w*4+quad, b = lane&15): register-local cell update.

__global__ __launch_bounds__(NTHREADS, 4)
void lstm_stack_mfma5(const float* __restrict__ x,
                      const float* __restrict__ W_ih0,
                      const float* __restrict__ W_hh0,
                      const float* __restrict__ b_ih0,
                      const float* __restrict__ b_hh0,
                      const float* __restrict__ W_ih1,
                      const float* __restrict__ W_hh1,
                      const float* __restrict__ b_ih1,
                      const float* __restrict__ b_hh1,
                      const float* __restrict__ W1,
                      const float* __restrict__ b1,
                      const float* __restrict__ W2,
                      const float* __restrict__ b2,
                      float* __restrict__ out)
{
    __shared__ alignas(16) unsigned short h_hi[2][NB][128];  // k 0..63=h1, 64..127=h2 (swizzled)
    __shared__ alignas(16) unsigned short x_pack[2][NB][32]; // [x_hi(5)|x_lo(5)|x_hi(5)|0..]
    __shared__ alignas(16) float h2f[NB][68];   // exact fp32 h2(T-1) for FC head
    __shared__ alignas(16) float zb[NB][36];    // FC-head z buffer

    const int tid  = threadIdx.x;
    const int b0   = blockIdx.x * NB;
    const int w    = tid >> 6;        // wave 0..15 = M-tile index (both layers)
    const int lane = tid & 63;
    const int n16  = lane & 15;       // A row (within tile) / B col / C col
    const int quad = lane >> 4;       // A k-group / C row-group

    // ---------------- persistent register state ----------------
    bf16x8 aXp;                       // L0 packed x-weights [Wx_hi|Wx_hi|Wx_lo]
    bf16x8 a0[4];                     // L0 h1: [Whi k0, Whi k1, Wlo k0, Wlo k1]
    bf16x8 a1[8];                     // L1 [h1;h2]: [Whi k0..3, Wlo k0..3]
    f32x4  bc0, bc1;                  // bias C-operands (VGPR)
    float  c0 = 0.f, c1 = 0.f;        // cell state (u = w*4+quad, b = n16)

    {
        const int u_a = w * 4 + (n16 >> 2);   // permuted u of this A row
        const int g_a = n16 & 3;              // gate of this A row
        const int r0  = g_a * 64 + u_a;       // original weight row
        float wv[8];
        // packed x K-tile: slots 0-4 Wx_hi, 5-9 Wx_hi, 10-14 Wx_lo, 15.. 0
        #pragma unroll
        for (int j = 0; j < 8; ++j) {
            const int k = quad * 8 + j;
            float v = 0.f;
            if (k < 2 * D_IN) {
                const float wf = W_ih0[r0 * D_IN + (k < D_IN ? k : k - D_IN)];
                v = bf2f(f2bf(wf));
            } else if (k < 3 * D_IN) {
                const float wf = W_ih0[r0 * D_IN + (k - 2 * D_IN)];
                v = wf - bf2f(f2bf(wf));
            }
            wv[j] = v;
        }
        bf16x8 dum;
        split8(wv, aXp, dum);         // values already bf16-exact
        #pragma unroll
        for (int kt = 0; kt < 2; ++kt) {
            #pragma unroll
            for (int j = 0; j < 8; ++j) wv[j] = W_hh0[r0 * 64 + kt * 32 + quad * 8 + j];
            split8(wv, a0[kt], a0[2 + kt]);
        }
        #pragma unroll
        for (int kt = 0; kt < 4; ++kt) {
            const int kg = kt * 32 + quad * 8;
            #pragma unroll
            for (int j = 0; j < 8; ++j)
                wv[j] = (kg < 64) ? W_ih1[r0 * 64 + kg + j] : W_hh1[r0 * 64 + (kg - 64) + j];
            split8(wv, a1[kt], a1[4 + kt]);
        }
        const int u_c = w * 4 + quad;
        #pragma unroll
        for (int r = 0; r < 4; ++r) {
            bc0[r] = b_ih0[r * 64 + u_c] + b_hh0[r * 64 + u_c];
            bc1[r] = b_ih1[r * 64 + u_c] + b_hh1[r * 64 + u_c];
        }
    }

    // ---------------- LDS init ----------------
    for (int i = tid; i < 2 * NB * 128; i += NTHREADS) (&h_hi[0][0][0])[i] = 0;
    for (int i = tid; i < 2 * NB * 32; i += NTHREADS) (&x_pack[0][0][0])[i] = 0;
    __syncthreads();
    const int xb = tid / D_IN, xd = tid % D_IN;   // x-staging role (tid < 80)
    const bool xrole = (tid < NB * D_IN);
    if (xrole) {   // x(t=0) into buffer 0
        const float xv = x[((size_t)(b0 + xb) * T_STEPS) * D_IN + xd];
        const unsigned short xh = f2bf(xv);
        const unsigned short xl = f2bf(xv - bf2f(xh));
        x_pack[0][xb][xd]             = xh;
        x_pack[0][xb][D_IN + xd]      = xl;
        x_pack[0][xb][2 * D_IN + xd]  = xh;
    }
    __syncthreads();

    const int u_c = w * 4 + quad;     // this lane's unit index, b = n16

    // step s: reads buf[s&1] = {h1(s-1), h2(s-2), x(s)}; computes gates0(s),
    // gates1(s-1); register-local epilogue; writes h1(s), h2(s-1), x(s+1)
    #pragma unroll 1
    for (int s = 0; s <= T_STEPS; ++s) {
        const int rb = s & 1, wbuf = rb ^ 1;

        float xv = 0.f;   // prefetch x(s+1)
        if (xrole && (s + 1) < T_STEPS)
            xv = x[((size_t)(b0 + xb) * T_STEPS + (s + 1)) * D_IN + xd];

        const bf16x8 bxp = *reinterpret_cast<const bf16x8*>(&x_pack[rb][n16][quad * 8]);
        bf16x8 bhh[4];
        #pragma unroll
        for (int kt = 0; kt < 4; ++kt)
            bhh[kt] = *reinterpret_cast<const bf16x8*>(
                &h_hi[rb][n16][((kt * 4 + quad) ^ (n16 & 7)) * 8]);

        f32x4 acc0, acc1;
        MFMA_INIT(acc0, aXp, bxp, bc0);        // bias + all 3 x split terms
        MFMA_ACC(acc0, a0[0], bhh[0]);         // Whi . h1
        MFMA_ACC(acc0, a0[1], bhh[1]);
        MFMA_ACC(acc0, a0[2], bhh[0]);         // Wlo . h1
        MFMA_ACC(acc0, a0[3], bhh[1]);

        MFMA_INIT(acc1, a1[0], bhh[0], bc1);   // Whi . [h1;h2]
        MFMA_ACC(acc1, a1[1], bhh[1]);
        MFMA_ACC(acc1, a1[2], bhh[2]);
        MFMA_ACC(acc1, a1[3], bhh[3]);
        MFMA_ACC(acc1, a1[4], bhh[0]);         // Wlo . [h1;h2]
        MFMA_ACC(acc1, a1[5], bhh[1]);
        MFMA_ACC(acc1, a1[6], bhh[2]);
        MFMA_ACC(acc1, a1[7], bhh[3]);

        // hazard spacing: MFMA D-write -> VALU read needs ~16 cyc
        asm("s_nop 7\n\ts_nop 7" : "+v"(acc0), "+v"(acc1));

        if (s < T_STEPS) {          // L0 epilogue: h1(s), c1
            const float i_ = fast_sigmoid(acc0[0]);
            const float f_ = fast_sigmoid(acc0[1]);
            const float g_ = fast_tanh(acc0[2]);
            const float o_ = fast_sigmoid(acc0[3]);
            const float c  = f_ * c0 + i_ * g_;
            c0 = c;
            const float h  = o_ * fast_tanh(c);
            h_hi[wbuf][n16][hswz(n16, u_c)] = f2bf(h);
        }
        if (s > 0) {                // L1 epilogue: h2(s-1), c2
            const float i_ = fast_sigmoid(acc1[0]);
            const float f_ = fast_sigmoid(acc1[1]);
            const float g_ = fast_tanh(acc1[2]);
            const float o_ = fast_sigmoid(acc1[3]);
            const float c  = f_ * c1 + i_ * g_;
            c1 = c;
            const float h  = o_ * fast_tanh(c);
            h_hi[wbuf][n16][hswz(n16, 64 + u_c)] = f2bf(h);
            if (s == T_STEPS) h2f[n16][u_c] = h;   // exact h2(T-1) for FC head
        }
        if (xrole && (s + 1) < T_STEPS) {   // stage x(s+1) packed
            const unsigned short xh = f2bf(xv);
            const unsigned short xl = f2bf(xv - bf2f(xh));
            x_pack[wbuf][xb][xd]            = xh;
            x_pack[wbuf][xb][D_IN + xd]     = xl;
            x_pack[wbuf][xb][2 * D_IN + xd] = xh;
        }
        __syncthreads();
    }

    // ---------------- FC head: relu(h2_T @ W1^T + b1) @ W2^T + b2 ----------------
    if (tid < 512) {
        const int bb = tid >> 5;            // 0..15
        const int k  = tid & 31;            // 0..31
        float a = b1[k];
        #pragma unroll 16
        for (int j = 0; j < 64; ++j)
            a = fmaf(W1[k * 64 + j], h2f[bb][j], a);
        zb[bb][k] = fmaxf(a, 0.0f);
    }
    __syncthreads();
    if (tid < NB) {
        float a = b2[0];
        #pragma unroll
        for (int k = 0; k < 32; ++k) a = fmaf(W2[k], zb[tid][k], a);
        out[b0 + tid] = a;
    }
}

extern "C" void kernel_launch(void* const* d_in, const int* in_sizes, int n_in,
                              void* d_out, int out_size, void* d_ws, size_t ws_size,
                              hipStream_t stream) {
    (void)in_sizes; (void)n_in; (void)d_ws; (void)ws_size;
    const float* xp     = (const float*)d_in[0];
    const float* W_ih0  = (const float*)d_in[1];
    const float* W_hh0  = (const float*)d_in[2];
    const float* b_ih0  = (const float*)d_in[3];
    const float* b_hh0  = (const float*)d_in[4];
    const float* W_ih1  = (const float*)d_in[5];
    const float* W_hh1  = (const float*)d_in[6];
    const float* b_ih1  = (const float*)d_in[7];
    const float* b_hh1  = (const float*)d_in[8];
    const float* W1     = (const float*)d_in[9];
    const float* b1     = (const float*)d_in[10];
    const float* W2     = (const float*)d_in[11];
    const float* b2     = (const float*)d_in[12];
    float* outp = (float*)d_out;

    const int nblocks = out_size / NB;   // 4096/16 = 256, one block per CU
    hipLaunchKernelGGL(lstm_stack_mfma5, dim3(nblocks), dim3(NTHREADS), 0, stream,
                       xp, W_ih0, W_hh0, b_ih0, b_hh0,
                       W_ih1, W_hh1, b_ih1, b_hh1,
                       W1, b1, W2, b2, outp);
}

// Round 8
// 567.950 us; speedup vs baseline: 1.7545x; 1.6617x over previous
//
#include <hip/hip_runtime.h>
#include <cstddef>

#define T_STEPS  512
#define D_IN     5
#define NB       16      // batch elements per block
#define NTHREADS 1024    // 16 waves; each wave owns 1 L0 M-tile + 1 L1 M-tile
#define LOG2E    1.4426950408889634f

typedef __attribute__((ext_vector_type(8))) short bf16x8;   // 8 bf16 (4 regs)
typedef __attribute__((ext_vector_type(4))) float f32x4;    // MFMA C/D

// A pinned in AGPRs ("a"); B, C, D in VGPRs (srcC and vDst must share a file).
#define MFMA_INIT(D, A, B, C) \
    asm("v_mfma_f32_16x16x32_bf16 %0, %1, %2, %3" : "=&v"(D) : "a"(A), "v"(B), "v"(C))
#define MFMA_ACC(D, A, B) \
    asm("v_mfma_f32_16x16x32_bf16 %0, %1, %2, %0" : "+v"(D) : "a"(A), "v"(B))

// Weights pre-scaled by log2e (2*log2e for g-gate rows), so activations use
// v_exp_f32 (2^x) directly -- no per-eval ln2 multiply, negation is a free
// VOP input modifier.
__device__ __forceinline__ float rcp1p(float t) {           // 1/(1+t)
    return __builtin_amdgcn_rcpf(1.0f + t);
}
__device__ __forceinline__ float sig2(float a) {            // sigmoid, a = log2e*x
    return rcp1p(__builtin_amdgcn_exp2f(-a));
}
__device__ __forceinline__ float tanh2(float a) {           // tanh, a = 2*log2e*x
    return 1.0f - 2.0f * rcp1p(__builtin_amdgcn_exp2f(a));
}

__device__ __forceinline__ unsigned short f2bf(float f) {   // RTNE fp32->bf16 bits
    unsigned int u = __float_as_uint(f);
    u += 0x7FFFu + ((u >> 16) & 1u);
    return (unsigned short)(u >> 16);
}
__device__ __forceinline__ float bf2f(unsigned short h) {
    return __uint_as_float(((unsigned int)h) << 16);
}
__device__ __forceinline__ void split8(const float* wv, bf16x8& hi, bf16x8& lo) {
    #pragma unroll
    for (int j = 0; j < 8; ++j) {
        unsigned short h = f2bf(wv[j]);
        unsigned short l = f2bf(wv[j] - bf2f(h));
        hi[j] = (short)h;
        lo[j] = (short)l;
    }
}

// h-plane swizzle: row = 128 u16 = 16 x 16B blocks; block j of row n lives at
// j ^ (n & 7). b128 reads conflict-free; scalar b16 writes 2-way (free).
__device__ __forceinline__ int hswz(int n, int col) {
    return (((col >> 3) ^ (n & 7)) << 3) | (col & 7);
}

__global__ __launch_bounds__(NTHREADS, 4)
void lstm_stack_mfma6(const float* __restrict__ x,
                      const float* __restrict__ W_ih0,
                      const float* __restrict__ W_hh0,
                      const float* __restrict__ b_ih0,
                      const float* __restrict__ b_hh0,
                      const float* __restrict__ W_ih1,
                      const float* __restrict__ W_hh1,
                      const float* __restrict__ b_ih1,
                      const float* __restrict__ b_hh1,
                      const float* __restrict__ W1,
                      const float* __restrict__ b1,
                      const float* __restrict__ W2,
                      const float* __restrict__ b2,
                      float* __restrict__ out)
{
    __shared__ alignas(16) unsigned short h_hi[2][NB][128];  // k 0..63=h1, 64..127=h2 (swizzled)
    // x tile row = 40 u16 (20 dw): bank = 4*((5*n16+quad)%8), a permutation
    // mod 8 -> 2-way only (the 32-u16 stride was an 8-way conflict: 16dw rows
    // collapse even/odd n16 onto 4 banks -- the dominant SQ_LDS_BANK_CONFLICT
    // source through R7).
    __shared__ alignas(16) unsigned short x_pack[2][NB][40]; // [x_hi(5)|x_lo(5)|x_hi(5)|0..]
    __shared__ alignas(16) float h2f[NB][68];   // exact fp32 h2(T-1) for FC head
    __shared__ alignas(16) float zb[NB][36];    // FC-head z buffer

    const int tid  = threadIdx.x;
    const int b0   = blockIdx.x * NB;
    const int w    = tid >> 6;        // wave 0..15 = M-tile index (both layers)
    const int lane = tid & 63;
    const int n16  = lane & 15;       // A row (within tile) / B col / C col
    const int quad = lane >> 4;       // A k-group / C row-group

    // ---------------- persistent register state ----------------
    bf16x8 aXp;                       // L0 packed x-weights [Wx_hi|Wx_hi|Wx_lo]
    bf16x8 a0[4];                     // L0 h1: [Whi k0, Whi k1, Wlo k0, Wlo k1]
    bf16x8 a1[8];                     // L1 [h1;h2]: [Whi k0..3, Wlo k0..3]
    f32x4  bc0, bc1;                  // bias C-operands (VGPR)
    float  c0 = 0.f, c1 = 0.f;        // cell state (u = w*4+quad, b = n16)

    {
        const int u_a = w * 4 + (n16 >> 2);   // permuted u of this A row
        const int g_a = n16 & 3;              // gate of this A row (i,f,g,o)
        const int r0  = g_a * 64 + u_a;       // original weight row
        const float sc = (g_a == 2) ? 2.0f * LOG2E : LOG2E;   // exp2 pre-scale
        float wv[8];
        // packed x K-tile: slots 0-4 Wx_hi, 5-9 Wx_hi, 10-14 Wx_lo, 15.. 0
        #pragma unroll
        for (int j = 0; j < 8; ++j) {
            const int k = quad * 8 + j;
            float v = 0.f;
            if (k < 2 * D_IN) {
                const float wf = sc * W_ih0[r0 * D_IN + (k < D_IN ? k : k - D_IN)];
                v = bf2f(f2bf(wf));
            } else if (k < 3 * D_IN) {
                const float wf = sc * W_ih0[r0 * D_IN + (k - 2 * D_IN)];
                v = wf - bf2f(f2bf(wf));
            }
            wv[j] = v;
        }
        bf16x8 dum;
        split8(wv, aXp, dum);         // values already bf16-exact
        #pragma unroll
        for (int kt = 0; kt < 2; ++kt) {
            #pragma unroll
            for (int j = 0; j < 8; ++j)
                wv[j] = sc * W_hh0[r0 * 64 + kt * 32 + quad * 8 + j];
            split8(wv, a0[kt], a0[2 + kt]);
        }
        #pragma unroll
        for (int kt = 0; kt < 4; ++kt) {
            const int kg = kt * 32 + quad * 8;
            #pragma unroll
            for (int j = 0; j < 8; ++j)
                wv[j] = sc * ((kg < 64) ? W_ih1[r0 * 64 + kg + j]
                                        : W_hh1[r0 * 64 + (kg - 64) + j]);
            split8(wv, a1[kt], a1[4 + kt]);
        }
        const int u_c = w * 4 + quad;
        #pragma unroll
        for (int r = 0; r < 4; ++r) {
            const float scr = (r == 2) ? 2.0f * LOG2E : LOG2E;
            bc0[r] = scr * (b_ih0[r * 64 + u_c] + b_hh0[r * 64 + u_c]);
            bc1[r] = scr * (b_ih1[r * 64 + u_c] + b_hh1[r * 64 + u_c]);
        }
    }

    // ---------------- LDS init ----------------
    for (int i = tid; i < 2 * NB * 128; i += NTHREADS) (&h_hi[0][0][0])[i] = 0;
    for (int i = tid; i < 2 * NB * 40; i += NTHREADS) (&x_pack[0][0][0])[i] = 0;
    __syncthreads();
    const int xb = tid / D_IN, xd = tid % D_IN;   // x-staging role (tid < 80)
    const bool xrole = (tid < NB * D_IN);
    if (xrole) {   // x(t=0) into buffer 0
        const float xv = x[((size_t)(b0 + xb) * T_STEPS) * D_IN + xd];
        const unsigned short xh = f2bf(xv);
        const unsigned short xl = f2bf(xv - bf2f(xh));
        x_pack[0][xb][xd]             = xh;
        x_pack[0][xb][D_IN + xd]      = xl;
        x_pack[0][xb][2 * D_IN + xd]  = xh;
    }
    __syncthreads();

    const int u_c = w * 4 + quad;     // this lane's unit index, b = n16

    // step s: reads buf[s&1] = {h1(s-1), h2(s-2), x(s)}; L0 chain -> L1 part1
    // -> epi0 (VALU overlaps other waves' MFMAs) -> L1 part2 -> epi1.
    #pragma unroll 1
    for (int s = 0; s <= T_STEPS; ++s) {
        const int rb = s & 1, wbuf = rb ^ 1;

        float xv = 0.f;   // prefetch x(s+1)
        if (xrole && (s + 1) < T_STEPS)
            xv = x[((size_t)(b0 + xb) * T_STEPS + (s + 1)) * D_IN + xd];

        const bf16x8 bxp = *reinterpret_cast<const bf16x8*>(&x_pack[rb][n16][quad * 8]);
        bf16x8 bhh[4];
        #pragma unroll
        for (int kt = 0; kt < 4; ++kt)
            bhh[kt] = *reinterpret_cast<const bf16x8*>(
                &h_hi[rb][n16][((kt * 4 + quad) ^ (n16 & 7)) * 8]);

        f32x4 acc0, acc1;
        // ---- L0 chain ----
        MFMA_INIT(acc0, aXp, bxp, bc0);        // bias + all 3 x split terms
        MFMA_ACC(acc0, a0[0], bhh[0]);         // Whi . h1
        MFMA_ACC(acc0, a0[1], bhh[1]);
        MFMA_ACC(acc0, a0[2], bhh[0]);         // Wlo . h1
        MFMA_ACC(acc0, a0[3], bhh[1]);
        // ---- L1 chain, part 1 ----
        MFMA_INIT(acc1, a1[0], bhh[0], bc1);   // Whi . [h1;h2]
        MFMA_ACC(acc1, a1[1], bhh[1]);
        MFMA_ACC(acc1, a1[2], bhh[2]);
        MFMA_ACC(acc1, a1[3], bhh[3]);

        // ---- L0 epilogue (acc0 hazard: 4 MFMA issues + nop > 16 cyc) ----
        asm("s_nop 7" : "+v"(acc0));
        if (s < T_STEPS) {
            const float i_ = sig2(acc0[0]);
            const float f_ = sig2(acc0[1]);
            const float g_ = tanh2(acc0[2]);
            const float o_ = sig2(acc0[3]);
            const float c  = f_ * c0 + i_ * g_;
            c0 = c;
            const float h  = o_ * tanh2(c * (2.0f * LOG2E));
            h_hi[wbuf][n16][hswz(n16, u_c)] = f2bf(h);
        }

        // ---- L1 chain, part 2 ----
        MFMA_ACC(acc1, a1[4], bhh[0]);         // Wlo . [h1;h2]
        MFMA_ACC(acc1, a1[5], bhh[1]);
        MFMA_ACC(acc1, a1[6], bhh[2]);
        MFMA_ACC(acc1, a1[7], bhh[3]);

        asm("s_nop 7\n\ts_nop 7" : "+v"(acc1));
        if (s > 0) {                // L1 epilogue: h2(s-1), c2
            const float i_ = sig2(acc1[0]);
            const float f_ = sig2(acc1[1]);
            const float g_ = tanh2(acc1[2]);
            const float o_ = sig2(acc1[3]);
            const float c  = f_ * c1 + i_ * g_;
            c1 = c;
            const float h  = o_ * tanh2(c * (2.0f * LOG2E));
            h_hi[wbuf][n16][hswz(n16, 64 + u_c)] = f2bf(h);
            if (s == T_STEPS) h2f[n16][u_c] = h;   // exact h2(T-1) for FC head
        }
        if (xrole && (s + 1) < T_STEPS) {   // stage x(s+1) packed
            const unsigned short xh = f2bf(xv);
            const unsigned short xl = f2bf(xv - bf2f(xh));
            x_pack[wbuf][xb][xd]            = xh;
            x_pack[wbuf][xb][D_IN + xd]     = xl;
            x_pack[wbuf][xb][2 * D_IN + xd] = xh;
        }
        __syncthreads();
    }

    // ---------------- FC head: relu(h2_T @ W1^T + b1) @ W2^T + b2 ----------------
    if (tid < 512) {
        const int bb = tid >> 5;            // 0..15
        const int k  = tid & 31;            // 0..31
        float a = b1[k];
        #pragma unroll 16
        for (int j = 0; j < 64; ++j)
            a = fmaf(W1[k * 64 + j], h2f[bb][j], a);
        zb[bb][k] = fmaxf(a, 0.0f);
    }
    __syncthreads();
    if (tid < NB) {
        float a = b2[0];
        #pragma unroll
        for (int k = 0; k < 32; ++k) a = fmaf(W2[k], zb[tid][k], a);
        out[b0 + tid] = a;
    }
}

extern "C" void kernel_launch(void* const* d_in, const int* in_sizes, int n_in,
                              void* d_out, int out_size, void* d_ws, size_t ws_size,
                              hipStream_t stream) {
    (void)in_sizes; (void)n_in; (void)d_ws; (void)ws_size;
    const float* xp     = (const float*)d_in[0];
    const float* W_ih0  = (const float*)d_in[1];
    const float* W_hh0  = (const float*)d_in[2];
    const float* b_ih0  = (const float*)d_in[3];
    const float* b_hh0  = (const float*)d_in[4];
    const float* W_ih1  = (const float*)d_in[5];
    const float* W_hh1  = (const float*)d_in[6];
    const float* b_ih1  = (const float*)d_in[7];
    const float* b_hh1  = (const float*)d_in[8];
    const float* W1     = (const float*)d_in[9];
    const float* b1     = (const float*)d_in[10];
    const float* W2     = (const float*)d_in[11];
    const float* b2     = (const float*)d_in[12];
    float* outp = (float*)d_out;

    const int nblocks = out_size / NB;   // 4096/16 = 256, one block per CU
    hipLaunchKernelGGL(lstm_stack_mfma6, dim3(nblocks), dim3(NTHREADS), 0, stream,
                       xp, W_ih0, W_hh0, b_ih0, b_hh0,
                       W_ih1, W_hh1, b_ih1, b_hh1,
                       W1, b1, W2, b2, outp);
}